// Round 13
// baseline (343.324 us; speedup 1.0000x reference)
//
#include <hip/hip_runtime.h>

// Hodgkin-Huxley synaptic network, Crank-Nicolson integration.
// R13 = R11 (best: 4-lane gate-parallel P/Q, reassociated membrane, off-spine
// fixup, 8-deep prefetch) + WAVE CO-RESIDENCY PACKING:
//   32 blocks x 512 threads = 8 waves/block -> 1 block/CU -> 2 waves/SIMD.
//   The SIMD interleaves the two waves: wave B issues during wave A's
//   rcp/exp spine stalls (R11 measured ~155cy issue + ~130cy stall per step).
//   Same program per chain -> bit-identical output to R11 (absmax 0.00390625).
// Serial spine per step: rcp(den) -> exp(Vn) -> rcp(Q). 256 waves total.

#if defined(__HIP_DEVICE_COMPILE__)
#define EXP2 __builtin_amdgcn_exp2f
#else
#define EXP2 exp2f
#endif

__device__ __forceinline__ float rcpf(float x) { return __builtin_amdgcn_rcpf(x); }

template<int CTRL>
__device__ __forceinline__ float qp(float x) {
#if defined(__HIP_DEVICE_COMPILE__)
    return __int_as_float(__builtin_amdgcn_mov_dpp(__float_as_int(x), CTRL, 0xF, 0xF, false));
#else
    return x;   // host pass: never executed, just needs to type-check
#endif
}
#define QB0(x) qp<0x00>(x)   // quad_perm broadcast lane 0
#define QB1(x) qp<0x55>(x)   // broadcast lane 1
#define QB2(x) qp<0xAA>(x)   // broadcast lane 2
#define QB3(x) qp<0xFF>(x)   // broadcast lane 3
#define QSW(x) qp<0xB1>(x)   // quad_perm[1,0,3,2]: lane^1 swap

struct LaneC {
    float cA, cB;            // e = exp2(fma(cA,Vn,cB))
    float cC, cD;            // t = fma(cC,Vn,cD)
    float cE;                // u = fma(-cE,e,1): 1-e (N,M) or 1 (H,y)
    float cH, cK, cL, cM;    // s = fma(cL,br, fma(cM,z, t*fma(cH,e,cK)))
    float cAe, cAz, cAt;     // alpha = fma(cAe,e, fma(cAz,z, cAt*t))
    float sing, fB, fA;      // Vn==sing -> g = fma(fB,g,fA)  (rcp-folded)
};

// One CN step for a 4-lane quad. g = this lane's gate (n/m/h/y). Returns Vn.
__device__ __forceinline__ float hh_step4(float& V, float& g, float z,
                                          const LaneC& C) {
    // gather gate values (quad broadcasts, VALU-speed)
    float nn = QB0(g), mm = QB1(g), hh2 = QB2(g), yy = QB3(g);
    // ---- membrane (redundant in all 4 lanes; bit-identical across quad) ----
    float m2 = mm * mm, mh = mm * hh2;
    float p1 = m2 * mh;                              // m^3 h  (GNA*DT/2 == 1)
    float q  = nn * nn, n4 = q * q;
    float gy1 = __builtin_fmaf(0.0125f, yy, 1.0025f);
    float den = p1 + __builtin_fmaf(0.875f, n4, gy1);   // 1 + G
    float rd  = rcpf(den);                              // long pole: start ASAP
    float t1  = __builtin_fmaf(110.0f, p1, -0.3f);
    float t2  = __builtin_fmaf(-134.75f, n4, t1);
    float pre = __builtin_fmaf(2.0f, V, t2);
    float num = __builtin_fmaf(-V, den, pre);           // == V(1-G) + DT(E+IAPP)
    float Vn  = num * rd;
    // ---- this lane's gate, P/Q rational form ----
    float e  = EXP2(__builtin_fmaf(C.cA, Vn, C.cB));
    float t  = __builtin_fmaf(C.cC, Vn, C.cD);
    bool fx  = (Vn == C.sing);                       // NaN sing on H,y -> false
    float br = QSW(e);                               // lane2 <- lane3's E4
    float w  = t * __builtin_fmaf(C.cH, e, C.cK);
    float s  = __builtin_fmaf(C.cL, br, __builtin_fmaf(C.cM, z, w));
    float u  = __builtin_fmaf(-C.cE, e, 1.0f);
    float Q  = u + s;
    float be = u - s;
    float al = __builtin_fmaf(C.cAe, e, __builtin_fmaf(C.cAz, z, C.cAt * t));
    float P  = __builtin_fmaf(be, g, al);
    float gN = P * rcpf(Q);
    float gF = __builtin_fmaf(C.fB, g, C.fA);        // parallel fixup value
    g = fx ? gF : gN;                                // one select, post-rcp
    V = Vn;
    return Vn;
}

__global__ __launch_bounds__(512, 1)
void hh_kernel(const float* __restrict__ z, float* __restrict__ out, int N) {
    const int gid   = blockIdx.x * 512 + threadIdx.x; // 0 .. 16383
    const int lane  = gid & 3;
    const int chain = gid >> 2;                      // 0 .. 4095
    const int b = chain >> 7;
    const int l = chain & 127;
    const size_t base = (size_t)b * N * 128 + l;
    const float* zp = z + base;
    float* op = out + base;

    // per-lane gate constants (exp2-domain; C9=1/(9ln2), C12=1/(12ln2))
    LaneC C;
    const float NaNf = __int_as_float(0x7FC00000);
    switch (lane) {
    case 0:  // N gate: e1 = exp((25-Vn)/9)
        C = { -0.1602994490f,  4.0074862250f,  0.02f, -0.5f, 1.0f,
              0.0025f, 0.025f, 0.0f, 0.0f,
              0.0f, 0.0f, 0.05f,
              25.0f, 0.98708396f, 0.0089418778f };   // 0.9935/1.0065, 0.009/1.0065
        break;
    case 1:  // M gate: e2 = exp((-35-Vn)/9)
        C = { -0.1602994490f, -5.6104807150f,  0.182f, 6.37f, 1.0f,
              0.0170329670329670f, 0.025f, 0.0f, 0.0f,
              0.0f, 0.0f, 0.05f,
              -35.0f, 0.86924620f, 0.076545632f };   // 0.93005/1.06995, 0.0819/1.06995
        break;
    case 2:  // H gate: E3 = exp((-90-Vn)/12); s = 0.00625(E3+br); alpha=0.0125E3
        C = { -0.1202245839f, -10.8202125510f, 0.0f, 1.0f, 0.0f,
              0.00625f, 0.0f, 0.00625f, 0.0f,
              0.0125f, 0.0f, 0.0f,
              NaNf, 0.0f, 0.0f };
        break;
    default: // y gate: E4 = exp((Vn+34)/12) (feeds lane2); s = 0.0025+0.025z
        C = {  0.1202245839f,   4.0876358530f, 0.0f, 1.0f, 0.0f,
              0.0f, 0.0025f, 0.0f, 0.025f,
              0.0f, 0.05f, 0.0f,
              NaNf, 0.0f, 0.0f };
        break;
    }

    float V = -70.0f;
    float g = (lane == 2) ? 1.0f : 0.0f;             // n=0, m=0, h=1, y=0

    op[0] = -70.0f;                                  // raw V0; pass 2 sigmoids it

    // 8-deep rotating prefetch: z0..z7 = z[t-1 .. t+6]
    float z0 = (0 <= N-2) ? zp[0]   : 0.0f;
    float z1 = (1 <= N-2) ? zp[128] : 0.0f;
    float z2 = (2 <= N-2) ? zp[256] : 0.0f;
    float z3 = (3 <= N-2) ? zp[384] : 0.0f;
    float z4 = (4 <= N-2) ? zp[512] : 0.0f;
    float z5 = (5 <= N-2) ? zp[640] : 0.0f;
    float z6 = (6 <= N-2) ? zp[768] : 0.0f;
    float z7 = (7 <= N-2) ? zp[896] : 0.0f;
    const float* zpre = zp + 8 * 128;                // next load: z[t+7] at t=1
    float* o = op + 128;
    int t = 1;
    // main: loads touch z indices t+7..t+10 <= N-1  ->  t <= N-11
    for (; t <= N - 11; t += 4) {
        float q0 = zpre[0];
        float q1 = zpre[128];
        float q2 = zpre[256];
        float q3 = zpre[384];
        zpre += 512;
        float v0 = hh_step4(V, g, z0, C);
        float v1 = hh_step4(V, g, z1, C);
        float v2 = hh_step4(V, g, z2, C);
        float v3 = hh_step4(V, g, z3, C);
        o[0] = v0; o[128] = v1; o[256] = v2; o[384] = v3;   // all lanes: same value
        o += 512;
        z0 = z4; z1 = z5; z2 = z6; z3 = z7;
        z4 = q0; z5 = q1; z6 = q2; z7 = q3;
    }
    // tail: per-step shift; refill z7 while in range
    for (; t < N; ++t) {
        float v0 = hh_step4(V, g, z0, C);
        *o = v0;
        o += 128;
        z0 = z1; z1 = z2; z2 = z3; z3 = z4; z4 = z5; z5 = z6; z6 = z7;
        z7 = (t + 7 <= N - 1) ? zpre[0] : 0.0f;      // z[t+7] for step t+8
        zpre += 128;
    }
}

// Pass 2: in-place sigmoid((v - VT)/KP) over the whole output, float4.
__global__ __launch_bounds__(256)
void sig_kernel(float4* __restrict__ v, int n4c) {
    int i = blockIdx.x * 256 + threadIdx.x;
    if (i < n4c) {
        float4 x = v[i];
        x.x = rcpf(1.0f + EXP2(__builtin_fmaf(-0.48089834664f, x.x, -9.6179669328f)));
        x.y = rcpf(1.0f + EXP2(__builtin_fmaf(-0.48089834664f, x.y, -9.6179669328f)));
        x.z = rcpf(1.0f + EXP2(__builtin_fmaf(-0.48089834664f, x.z, -9.6179669328f)));
        x.w = rcpf(1.0f + EXP2(__builtin_fmaf(-0.48089834664f, x.w, -9.6179669328f)));
        v[i] = x;
    }
}

extern "C" void kernel_launch(void* const* d_in, const int* in_sizes, int n_in,
                              void* d_out, int out_size, void* d_ws, size_t ws_size,
                              hipStream_t stream) {
    const float* z = (const float*)d_in[0];
    float* out = (float*)d_out;
    const int B = 32, L = 128;
    const int N = in_sizes[0] / (B * L);             // 2000
    // 32 blocks x 512 threads: 8 waves/block -> 1 block/CU -> 2 waves/SIMD.
    dim3 grid(B * L * 4 / 512), block(512);
    hipLaunchKernelGGL(hh_kernel, grid, block, 0, stream, z, out, N);
    const int n4c = out_size / 4;                    // out_size divisible by 4
    dim3 sgrid((n4c + 255) / 256), sblock(256);
    hipLaunchKernelGGL(sig_kernel, sgrid, sblock, 0, stream, (float4*)out, n4c);
}

// Round 14
// 327.026 us; speedup vs baseline: 1.0498x; 1.0498x over previous
//
#include <hip/hip_runtime.h>

// Hodgkin-Huxley synaptic network, Crank-Nicolson integration.
// R14 = R11 (4-lane gate-parallel P/Q form, reassociated membrane, off-spine
// singularity fixup, 8-deep prefetch) + TWO CHAINS PER THREAD, interleaved.
// R11 measured ~54% per-SIMD issue busy (spine stalls: rcp->exp->rcp). A
// second, register-independent chain in the same thread fills those stalls
// (R13 proved cross-stream interleave gains ~1.25x per SIMD; in-thread
// interleave avoids R13's CU-concentration penalty).
// 128 blocks x 64 threads = 128 waves on 128 CUs (1/SIMD). Each thread is one
// quad-lane role for chain A (quad id) and chain B (quad id + 2048).
// Per-chain arithmetic identical to R11 -> absmax bit-identical 0.00390625.

#if defined(__HIP_DEVICE_COMPILE__)
#define EXP2 __builtin_amdgcn_exp2f
#else
#define EXP2 exp2f
#endif

__device__ __forceinline__ float rcpf(float x) { return __builtin_amdgcn_rcpf(x); }

template<int CTRL>
__device__ __forceinline__ float qp(float x) {
#if defined(__HIP_DEVICE_COMPILE__)
    return __int_as_float(__builtin_amdgcn_mov_dpp(__float_as_int(x), CTRL, 0xF, 0xF, false));
#else
    return x;   // host pass: never executed, just needs to type-check
#endif
}
#define QB0(x) qp<0x00>(x)   // quad_perm broadcast lane 0
#define QB1(x) qp<0x55>(x)   // broadcast lane 1
#define QB2(x) qp<0xAA>(x)   // broadcast lane 2
#define QB3(x) qp<0xFF>(x)   // broadcast lane 3
#define QSW(x) qp<0xB1>(x)   // quad_perm[1,0,3,2]: lane^1 swap

struct LaneC {
    float cA, cB;            // e = exp2(fma(cA,Vn,cB))
    float cC, cD;            // t = fma(cC,Vn,cD)
    float cE;                // u = fma(-cE,e,1): 1-e (N,M) or 1 (H,y)
    float cH, cK, cL, cM;    // s = fma(cL,br, fma(cM,z, t*fma(cH,e,cK)))
    float cAe, cAz, cAt;     // alpha = fma(cAe,e, fma(cAz,z, cAt*t))
    float sing, fB, fA;      // Vn==sing -> g = fma(fB,g,fA)  (rcp-folded)
};

// One CN step for a 4-lane quad. g = this lane's gate (n/m/h/y). Returns Vn.
__device__ __forceinline__ float hh_step4(float& V, float& g, float z,
                                          const LaneC& C) {
    // gather gate values (quad broadcasts, VALU-speed)
    float nn = QB0(g), mm = QB1(g), hh2 = QB2(g), yy = QB3(g);
    // ---- membrane (redundant in all 4 lanes; bit-identical across quad) ----
    float m2 = mm * mm, mh = mm * hh2;
    float p1 = m2 * mh;                              // m^3 h  (GNA*DT/2 == 1)
    float q  = nn * nn, n4 = q * q;
    float gy1 = __builtin_fmaf(0.0125f, yy, 1.0025f);
    float den = p1 + __builtin_fmaf(0.875f, n4, gy1);   // 1 + G
    float rd  = rcpf(den);                              // long pole: start ASAP
    float t1  = __builtin_fmaf(110.0f, p1, -0.3f);
    float t2  = __builtin_fmaf(-134.75f, n4, t1);
    float pre = __builtin_fmaf(2.0f, V, t2);
    float num = __builtin_fmaf(-V, den, pre);           // == V(1-G) + DT(E+IAPP)
    float Vn  = num * rd;
    // ---- this lane's gate, P/Q rational form ----
    float e  = EXP2(__builtin_fmaf(C.cA, Vn, C.cB));
    float t  = __builtin_fmaf(C.cC, Vn, C.cD);
    bool fx  = (Vn == C.sing);                       // NaN sing on H,y -> false
    float br = QSW(e);                               // lane2 <- lane3's E4
    float w  = t * __builtin_fmaf(C.cH, e, C.cK);
    float s  = __builtin_fmaf(C.cL, br, __builtin_fmaf(C.cM, z, w));
    float u  = __builtin_fmaf(-C.cE, e, 1.0f);
    float Q  = u + s;
    float be = u - s;
    float al = __builtin_fmaf(C.cAe, e, __builtin_fmaf(C.cAz, z, C.cAt * t));
    float P  = __builtin_fmaf(be, g, al);
    float gN = P * rcpf(Q);
    float gF = __builtin_fmaf(C.fB, g, C.fA);        // parallel fixup value
    g = fx ? gF : gN;                                // one select, post-rcp
    V = Vn;
    return Vn;
}

__global__ __launch_bounds__(64, 1)
void hh_kernel(const float* __restrict__ z, float* __restrict__ out, int N) {
    const int gid   = blockIdx.x * 64 + threadIdx.x; // 0 .. 8191
    const int lane  = gid & 3;
    const int quad  = gid >> 2;                      // 0 .. 2047
    // chain A = quad, chain B = quad + 2048
    const int bA = quad >> 7,          lA = quad & 127;
    const int bB = (quad + 2048) >> 7, lB = (quad + 2048) & 127;
    const size_t baseA = (size_t)bA * N * 128 + lA;
    const size_t baseB = (size_t)bB * N * 128 + lB;
    const float* zpA = z + baseA;
    const float* zpB = z + baseB;
    float* opA = out + baseA;
    float* opB = out + baseB;

    // per-lane gate constants (exp2-domain; C9=1/(9ln2), C12=1/(12ln2))
    LaneC C;
    const float NaNf = __int_as_float(0x7FC00000);
    switch (lane) {
    case 0:  // N gate: e1 = exp((25-Vn)/9)
        C = { -0.1602994490f,  4.0074862250f,  0.02f, -0.5f, 1.0f,
              0.0025f, 0.025f, 0.0f, 0.0f,
              0.0f, 0.0f, 0.05f,
              25.0f, 0.98708396f, 0.0089418778f };   // 0.9935/1.0065, 0.009/1.0065
        break;
    case 1:  // M gate: e2 = exp((-35-Vn)/9)
        C = { -0.1602994490f, -5.6104807150f,  0.182f, 6.37f, 1.0f,
              0.0170329670329670f, 0.025f, 0.0f, 0.0f,
              0.0f, 0.0f, 0.05f,
              -35.0f, 0.86924620f, 0.076545632f };   // 0.93005/1.06995, 0.0819/1.06995
        break;
    case 2:  // H gate: E3 = exp((-90-Vn)/12); s = 0.00625(E3+br); alpha=0.0125E3
        C = { -0.1202245839f, -10.8202125510f, 0.0f, 1.0f, 0.0f,
              0.00625f, 0.0f, 0.00625f, 0.0f,
              0.0125f, 0.0f, 0.0f,
              NaNf, 0.0f, 0.0f };
        break;
    default: // y gate: E4 = exp((Vn+34)/12) (feeds lane2); s = 0.0025+0.025z
        C = {  0.1202245839f,   4.0876358530f, 0.0f, 1.0f, 0.0f,
              0.0f, 0.0025f, 0.0f, 0.025f,
              0.0f, 0.05f, 0.0f,
              NaNf, 0.0f, 0.0f };
        break;
    }

    float VA = -70.0f, VB = -70.0f;
    float gA = (lane == 2) ? 1.0f : 0.0f;            // n=0, m=0, h=1, y=0
    float gB = gA;

    opA[0] = -70.0f;                                 // raw V0; pass 2 sigmoids it
    opB[0] = -70.0f;

    // 8-deep rotating prefetch per chain: a0..a7 = zA[t-1 .. t+6], b likewise
    float a0 = (0 <= N-2) ? zpA[0]   : 0.0f,  b0 = (0 <= N-2) ? zpB[0]   : 0.0f;
    float a1 = (1 <= N-2) ? zpA[128] : 0.0f,  b1 = (1 <= N-2) ? zpB[128] : 0.0f;
    float a2 = (2 <= N-2) ? zpA[256] : 0.0f,  b2 = (2 <= N-2) ? zpB[256] : 0.0f;
    float a3 = (3 <= N-2) ? zpA[384] : 0.0f,  b3 = (3 <= N-2) ? zpB[384] : 0.0f;
    float a4 = (4 <= N-2) ? zpA[512] : 0.0f,  b4 = (4 <= N-2) ? zpB[512] : 0.0f;
    float a5 = (5 <= N-2) ? zpA[640] : 0.0f,  b5 = (5 <= N-2) ? zpB[640] : 0.0f;
    float a6 = (6 <= N-2) ? zpA[768] : 0.0f,  b6 = (6 <= N-2) ? zpB[768] : 0.0f;
    float a7 = (7 <= N-2) ? zpA[896] : 0.0f,  b7 = (7 <= N-2) ? zpB[896] : 0.0f;
    const float* zpreA = zpA + 8 * 128;              // next load: z[t+7] at t=1
    const float* zpreB = zpB + 8 * 128;
    float* oA = opA + 128;
    float* oB = opB + 128;
    int t = 1;
    // main: loads touch z indices t+7..t+10 <= N-1  ->  t <= N-11
    for (; t <= N - 11; t += 4) {
        float qa0 = zpreA[0],   qb0 = zpreB[0];
        float qa1 = zpreA[128], qb1 = zpreB[128];
        float qa2 = zpreA[256], qb2 = zpreB[256];
        float qa3 = zpreA[384], qb3 = zpreB[384];
        zpreA += 512; zpreB += 512;
        // interleaved A/B steps: B's issue fills A's spine stalls & vice versa
        float vA0 = hh_step4(VA, gA, a0, C);
        float vB0 = hh_step4(VB, gB, b0, C);
        float vA1 = hh_step4(VA, gA, a1, C);
        float vB1 = hh_step4(VB, gB, b1, C);
        float vA2 = hh_step4(VA, gA, a2, C);
        float vB2 = hh_step4(VB, gB, b2, C);
        float vA3 = hh_step4(VA, gA, a3, C);
        float vB3 = hh_step4(VB, gB, b3, C);
        oA[0] = vA0; oA[128] = vA1; oA[256] = vA2; oA[384] = vA3;
        oB[0] = vB0; oB[128] = vB1; oB[256] = vB2; oB[384] = vB3;
        oA += 512; oB += 512;
        a0 = a4; a1 = a5; a2 = a6; a3 = a7;
        a4 = qa0; a5 = qa1; a6 = qa2; a7 = qa3;
        b0 = b4; b1 = b5; b2 = b6; b3 = b7;
        b4 = qb0; b5 = qb1; b6 = qb2; b7 = qb3;
    }
    // tail: per-step shift; refill window while in range
    for (; t < N; ++t) {
        float vA0 = hh_step4(VA, gA, a0, C);
        float vB0 = hh_step4(VB, gB, b0, C);
        *oA = vA0; *oB = vB0;
        oA += 128; oB += 128;
        a0 = a1; a1 = a2; a2 = a3; a3 = a4; a4 = a5; a5 = a6; a6 = a7;
        b0 = b1; b1 = b2; b2 = b3; b3 = b4; b4 = b5; b5 = b6; b6 = b7;
        bool ok = (t + 7 <= N - 1);
        a7 = ok ? zpreA[0] : 0.0f;
        b7 = ok ? zpreB[0] : 0.0f;
        zpreA += 128; zpreB += 128;
    }
}

// Pass 2: in-place sigmoid((v - VT)/KP) over the whole output, float4.
__global__ __launch_bounds__(256)
void sig_kernel(float4* __restrict__ v, int n4c) {
    int i = blockIdx.x * 256 + threadIdx.x;
    if (i < n4c) {
        float4 x = v[i];
        x.x = rcpf(1.0f + EXP2(__builtin_fmaf(-0.48089834664f, x.x, -9.6179669328f)));
        x.y = rcpf(1.0f + EXP2(__builtin_fmaf(-0.48089834664f, x.y, -9.6179669328f)));
        x.z = rcpf(1.0f + EXP2(__builtin_fmaf(-0.48089834664f, x.z, -9.6179669328f)));
        x.w = rcpf(1.0f + EXP2(__builtin_fmaf(-0.48089834664f, x.w, -9.6179669328f)));
        v[i] = x;
    }
}

extern "C" void kernel_launch(void* const* d_in, const int* in_sizes, int n_in,
                              void* d_out, int out_size, void* d_ws, size_t ws_size,
                              hipStream_t stream) {
    const float* z = (const float*)d_in[0];
    float* out = (float*)d_out;
    const int B = 32, L = 128;
    const int N = in_sizes[0] / (B * L);             // 2000
    // 4096 chains x 4 lanes / 2 chains-per-thread = 8192 threads = 128 blocks
    dim3 grid(B * L * 4 / (2 * 64)), block(64);
    hipLaunchKernelGGL(hh_kernel, grid, block, 0, stream, z, out, N);
    const int n4c = out_size / 4;                    // out_size divisible by 4
    dim3 sgrid((n4c + 255) / 256), sblock(256);
    hipLaunchKernelGGL(sig_kernel, sgrid, sblock, 0, stream, (float4*)out, n4c);
}

// Round 15
// 238.095 us; speedup vs baseline: 1.4420x; 1.3735x over previous
//
#include <hip/hip_runtime.h>

// Hodgkin-Huxley synaptic network, Crank-Nicolson integration.
// R15 = R11 (best: 4-lane gate-parallel P/Q form, reassociated membrane,
// off-spine singularity fixup, 8-deep prefetch, 256 waves) + spine shavings:
//   - exp-arg fusion: e = exp2(fma(cA*num, rd, cB)) with cA*num computed in
//     the rcp(den) latency shadow -> drops the Vn-mul from the V->exp spine.
//   - t = fma(cC*num, rd, cD) likewise. Vn still computed (store + fixup cmp).
// Structural map (R4/R12/R13/R14 falsified alternatives): 4096 chains x 4
// lanes = 256 waves max; 1 wave/SIMD; wall = N x per-step wave time
// (~286cy = ~140 issue + spine rcp->exp->rcp latency).

#if defined(__HIP_DEVICE_COMPILE__)
#define EXP2 __builtin_amdgcn_exp2f
#else
#define EXP2 exp2f
#endif

__device__ __forceinline__ float rcpf(float x) { return __builtin_amdgcn_rcpf(x); }

template<int CTRL>
__device__ __forceinline__ float qp(float x) {
#if defined(__HIP_DEVICE_COMPILE__)
    return __int_as_float(__builtin_amdgcn_mov_dpp(__float_as_int(x), CTRL, 0xF, 0xF, false));
#else
    return x;   // host pass: never executed, just needs to type-check
#endif
}
#define QB0(x) qp<0x00>(x)   // quad_perm broadcast lane 0
#define QB1(x) qp<0x55>(x)   // broadcast lane 1
#define QB2(x) qp<0xAA>(x)   // broadcast lane 2
#define QB3(x) qp<0xFF>(x)   // broadcast lane 3
#define QSW(x) qp<0xB1>(x)   // quad_perm[1,0,3,2]: lane^1 swap

struct LaneC {
    float cA, cB;            // e = exp2(cA*Vn + cB)   (applied as fused form)
    float cC, cD;            // t = cC*Vn + cD
    float cE;                // u = fma(-cE,e,1): 1-e (N,M) or 1 (H,y)
    float cH, cK, cL, cM;    // s = fma(cL,br, fma(cM,z, t*fma(cH,e,cK)))
    float cAe, cAz, cAt;     // alpha = fma(cAe,e, fma(cAz,z, cAt*t))
    float sing, fB, fA;      // Vn==sing -> g = fma(fB,g,fA)  (rcp-folded)
};

// One CN step for a 4-lane quad. g = this lane's gate (n/m/h/y). Returns Vn.
__device__ __forceinline__ float hh_step4(float& V, float& g, float z,
                                          const LaneC& C) {
    // gather gate values (quad broadcasts, VALU-speed)
    float nn = QB0(g), mm = QB1(g), hh2 = QB2(g), yy = QB3(g);
    // ---- membrane (redundant in all 4 lanes; bit-identical across quad) ----
    float m2 = mm * mm, mh = mm * hh2;
    float p1 = m2 * mh;                              // m^3 h  (GNA*DT/2 == 1)
    float q  = nn * nn, n4 = q * q;
    float gy1 = __builtin_fmaf(0.0125f, yy, 1.0025f);
    float den = p1 + __builtin_fmaf(0.875f, n4, gy1);   // 1 + G
    float rd  = rcpf(den);                              // long pole: start ASAP
    float t1  = __builtin_fmaf(110.0f, p1, -0.3f);
    float t2  = __builtin_fmaf(-134.75f, n4, t1);
    float pre = __builtin_fmaf(2.0f, V, t2);
    float num = __builtin_fmaf(-V, den, pre);           // == V(1-G) + DT(E+IAPP)
    // fused spine feeds (computed in rcp's shadow):
    float numA = C.cA * num;                            // -> exp arg
    float numC = C.cC * num;                            // -> t
    float Vn  = num * rd;                               // for store + fixup cmp
    // ---- this lane's gate, P/Q rational form ----
    float e  = EXP2(__builtin_fmaf(numA, rd, C.cB));    // == exp2(cA*Vn+cB)
    float t  = __builtin_fmaf(numC, rd, C.cD);          // == cC*Vn+cD
    bool fx  = (Vn == C.sing);                       // NaN sing on H,y -> false
    float br = QSW(e);                               // lane2 <- lane3's E4
    float w  = t * __builtin_fmaf(C.cH, e, C.cK);
    float s  = __builtin_fmaf(C.cL, br, __builtin_fmaf(C.cM, z, w));
    float u  = __builtin_fmaf(-C.cE, e, 1.0f);
    float Q  = u + s;
    float be = u - s;
    float al = __builtin_fmaf(C.cAe, e, __builtin_fmaf(C.cAz, z, C.cAt * t));
    float P  = __builtin_fmaf(be, g, al);
    float gN = P * rcpf(Q);
    float gF = __builtin_fmaf(C.fB, g, C.fA);        // parallel fixup value
    g = fx ? gF : gN;                                // one select, post-rcp
    V = Vn;
    return Vn;
}

__global__ __launch_bounds__(64, 1)
void hh_kernel(const float* __restrict__ z, float* __restrict__ out, int N) {
    const int gid   = blockIdx.x * 64 + threadIdx.x; // 0 .. 16383
    const int lane  = gid & 3;
    const int chain = gid >> 2;                      // 0 .. 4095
    const int b = chain >> 7;
    const int l = chain & 127;
    const size_t base = (size_t)b * N * 128 + l;
    const float* zp = z + base;
    float* op = out + base;

    // per-lane gate constants (exp2-domain; C9=1/(9ln2), C12=1/(12ln2))
    LaneC C;
    const float NaNf = __int_as_float(0x7FC00000);
    switch (lane) {
    case 0:  // N gate: e1 = exp((25-Vn)/9)
        C = { -0.1602994490f,  4.0074862250f,  0.02f, -0.5f, 1.0f,
              0.0025f, 0.025f, 0.0f, 0.0f,
              0.0f, 0.0f, 0.05f,
              25.0f, 0.98708396f, 0.0089418778f };   // 0.9935/1.0065, 0.009/1.0065
        break;
    case 1:  // M gate: e2 = exp((-35-Vn)/9)
        C = { -0.1602994490f, -5.6104807150f,  0.182f, 6.37f, 1.0f,
              0.0170329670329670f, 0.025f, 0.0f, 0.0f,
              0.0f, 0.0f, 0.05f,
              -35.0f, 0.86924620f, 0.076545632f };   // 0.93005/1.06995, 0.0819/1.06995
        break;
    case 2:  // H gate: E3 = exp((-90-Vn)/12); s = 0.00625(E3+br); alpha=0.0125E3
        C = { -0.1202245839f, -10.8202125510f, 0.0f, 1.0f, 0.0f,
              0.00625f, 0.0f, 0.00625f, 0.0f,
              0.0125f, 0.0f, 0.0f,
              NaNf, 0.0f, 0.0f };
        break;
    default: // y gate: E4 = exp((Vn+34)/12) (feeds lane2); s = 0.0025+0.025z
        C = {  0.1202245839f,   4.0876358530f, 0.0f, 1.0f, 0.0f,
              0.0f, 0.0025f, 0.0f, 0.025f,
              0.0f, 0.05f, 0.0f,
              NaNf, 0.0f, 0.0f };
        break;
    }

    float V = -70.0f;
    float g = (lane == 2) ? 1.0f : 0.0f;             // n=0, m=0, h=1, y=0

    op[0] = -70.0f;                                  // raw V0; pass 2 sigmoids it

    // 8-deep rotating prefetch: z0..z7 = z[t-1 .. t+6]
    float z0 = (0 <= N-2) ? zp[0]   : 0.0f;
    float z1 = (1 <= N-2) ? zp[128] : 0.0f;
    float z2 = (2 <= N-2) ? zp[256] : 0.0f;
    float z3 = (3 <= N-2) ? zp[384] : 0.0f;
    float z4 = (4 <= N-2) ? zp[512] : 0.0f;
    float z5 = (5 <= N-2) ? zp[640] : 0.0f;
    float z6 = (6 <= N-2) ? zp[768] : 0.0f;
    float z7 = (7 <= N-2) ? zp[896] : 0.0f;
    const float* zpre = zp + 8 * 128;                // next load: z[t+7] at t=1
    float* o = op + 128;
    int t = 1;
    // main: loads touch z indices t+7..t+10 <= N-1  ->  t <= N-11
    for (; t <= N - 11; t += 4) {
        float q0 = zpre[0];
        float q1 = zpre[128];
        float q2 = zpre[256];
        float q3 = zpre[384];
        zpre += 512;
        float v0 = hh_step4(V, g, z0, C);
        float v1 = hh_step4(V, g, z1, C);
        float v2 = hh_step4(V, g, z2, C);
        float v3 = hh_step4(V, g, z3, C);
        o[0] = v0; o[128] = v1; o[256] = v2; o[384] = v3;   // all lanes: same value
        o += 512;
        z0 = z4; z1 = z5; z2 = z6; z3 = z7;
        z4 = q0; z5 = q1; z6 = q2; z7 = q3;
    }
    // tail: per-step shift; refill z7 while in range
    for (; t < N; ++t) {
        float v0 = hh_step4(V, g, z0, C);
        *o = v0;
        o += 128;
        z0 = z1; z1 = z2; z2 = z3; z3 = z4; z4 = z5; z5 = z6; z6 = z7;
        z7 = (t + 7 <= N - 1) ? zpre[0] : 0.0f;      // z[t+7] for step t+8
        zpre += 128;
    }
}

// Pass 2: in-place sigmoid((v - VT)/KP) over the whole output, float4.
__global__ __launch_bounds__(256)
void sig_kernel(float4* __restrict__ v, int n4c) {
    int i = blockIdx.x * 256 + threadIdx.x;
    if (i < n4c) {
        float4 x = v[i];
        x.x = rcpf(1.0f + EXP2(__builtin_fmaf(-0.48089834664f, x.x, -9.6179669328f)));
        x.y = rcpf(1.0f + EXP2(__builtin_fmaf(-0.48089834664f, x.y, -9.6179669328f)));
        x.z = rcpf(1.0f + EXP2(__builtin_fmaf(-0.48089834664f, x.z, -9.6179669328f)));
        x.w = rcpf(1.0f + EXP2(__builtin_fmaf(-0.48089834664f, x.w, -9.6179669328f)));
        v[i] = x;
    }
}

extern "C" void kernel_launch(void* const* d_in, const int* in_sizes, int n_in,
                              void* d_out, int out_size, void* d_ws, size_t ws_size,
                              hipStream_t stream) {
    const float* z = (const float*)d_in[0];
    float* out = (float*)d_out;
    const int B = 32, L = 128;
    const int N = in_sizes[0] / (B * L);             // 2000
    dim3 grid(B * L * 4 / 64), block(64);            // 4 lanes/chain -> 256 waves
    hipLaunchKernelGGL(hh_kernel, grid, block, 0, stream, z, out, N);
    const int n4c = out_size / 4;                    // out_size divisible by 4
    dim3 sgrid((n4c + 255) / 256), sblock(256);
    hipLaunchKernelGGL(sig_kernel, sgrid, sblock, 0, stream, (float4*)out, n4c);
}

// Round 16
// 217.109 us; speedup vs baseline: 1.5813x; 1.0967x over previous
//
#include <hip/hip_runtime.h>

// Hodgkin-Huxley synaptic network, Crank-Nicolson integration.
// R16 = R11 verbatim (best measured: 218 us). 4-lane gate-parallel P/Q form,
// reassociated membrane (rcp starts early, num in its shadow), off-spine
// singularity fixup, 8-deep z prefetch, separate sigmoid pass.
// Structural floor (established R4-R15): 4096 chains x 4 lanes = 256 waves =
// 1 wave/SIMD; wall = N x per-step wave time (~286cy = ~140cy issue +
// rcp->exp->rcp spine latency). All alternative structures measured worse:
//   R5 cross-wave split (barrier cost), R12 common-denominator (glue > rcp),
//   R13 co-residency packing (CU concentration), R14 dual-chain (wave halving).

#if defined(__HIP_DEVICE_COMPILE__)
#define EXP2 __builtin_amdgcn_exp2f
#else
#define EXP2 exp2f
#endif

__device__ __forceinline__ float rcpf(float x) { return __builtin_amdgcn_rcpf(x); }

template<int CTRL>
__device__ __forceinline__ float qp(float x) {
#if defined(__HIP_DEVICE_COMPILE__)
    return __int_as_float(__builtin_amdgcn_mov_dpp(__float_as_int(x), CTRL, 0xF, 0xF, false));
#else
    return x;   // host pass: never executed, just needs to type-check
#endif
}
#define QB0(x) qp<0x00>(x)   // quad_perm broadcast lane 0
#define QB1(x) qp<0x55>(x)   // broadcast lane 1
#define QB2(x) qp<0xAA>(x)   // broadcast lane 2
#define QB3(x) qp<0xFF>(x)   // broadcast lane 3
#define QSW(x) qp<0xB1>(x)   // quad_perm[1,0,3,2]: lane^1 swap

struct LaneC {
    float cA, cB;            // e = exp2(fma(cA,Vn,cB))
    float cC, cD;            // t = fma(cC,Vn,cD)
    float cE;                // u = fma(-cE,e,1): 1-e (N,M) or 1 (H,y)
    float cH, cK, cL, cM;    // s = fma(cL,br, fma(cM,z, t*fma(cH,e,cK)))
    float cAe, cAz, cAt;     // alpha = fma(cAe,e, fma(cAz,z, cAt*t))
    float sing, fB, fA;      // Vn==sing -> g = fma(fB,g,fA)  (rcp-folded)
};

// One CN step for a 4-lane quad. g = this lane's gate (n/m/h/y). Returns Vn.
__device__ __forceinline__ float hh_step4(float& V, float& g, float z,
                                          const LaneC& C) {
    // gather gate values (quad broadcasts, VALU-speed)
    float nn = QB0(g), mm = QB1(g), hh2 = QB2(g), yy = QB3(g);
    // ---- membrane (redundant in all 4 lanes; bit-identical across quad) ----
    float m2 = mm * mm, mh = mm * hh2;
    float p1 = m2 * mh;                              // m^3 h  (GNA*DT/2 == 1)
    float q  = nn * nn, n4 = q * q;
    float gy1 = __builtin_fmaf(0.0125f, yy, 1.0025f);
    float den = p1 + __builtin_fmaf(0.875f, n4, gy1);   // 1 + G
    float rd  = rcpf(den);                              // long pole: start ASAP
    float t1  = __builtin_fmaf(110.0f, p1, -0.3f);
    float t2  = __builtin_fmaf(-134.75f, n4, t1);
    float pre = __builtin_fmaf(2.0f, V, t2);
    float num = __builtin_fmaf(-V, den, pre);           // == V(1-G) + DT(E+IAPP)
    float Vn  = num * rd;
    // ---- this lane's gate, P/Q rational form ----
    float e  = EXP2(__builtin_fmaf(C.cA, Vn, C.cB));
    float t  = __builtin_fmaf(C.cC, Vn, C.cD);
    bool fx  = (Vn == C.sing);                       // NaN sing on H,y -> false
    float br = QSW(e);                               // lane2 <- lane3's E4
    float w  = t * __builtin_fmaf(C.cH, e, C.cK);
    float s  = __builtin_fmaf(C.cL, br, __builtin_fmaf(C.cM, z, w));
    float u  = __builtin_fmaf(-C.cE, e, 1.0f);
    float Q  = u + s;
    float be = u - s;
    float al = __builtin_fmaf(C.cAe, e, __builtin_fmaf(C.cAz, z, C.cAt * t));
    float P  = __builtin_fmaf(be, g, al);
    float gN = P * rcpf(Q);
    float gF = __builtin_fmaf(C.fB, g, C.fA);        // parallel fixup value
    g = fx ? gF : gN;                                // one select, post-rcp
    V = Vn;
    return Vn;
}

__global__ __launch_bounds__(64, 1)
void hh_kernel(const float* __restrict__ z, float* __restrict__ out, int N) {
    const int gid   = blockIdx.x * 64 + threadIdx.x; // 0 .. 16383
    const int lane  = gid & 3;
    const int chain = gid >> 2;                      // 0 .. 4095
    const int b = chain >> 7;
    const int l = chain & 127;
    const size_t base = (size_t)b * N * 128 + l;
    const float* zp = z + base;
    float* op = out + base;

    // per-lane gate constants (exp2-domain; C9=1/(9ln2), C12=1/(12ln2))
    LaneC C;
    const float NaNf = __int_as_float(0x7FC00000);
    switch (lane) {
    case 0:  // N gate: e1 = exp((25-Vn)/9)
        C = { -0.1602994490f,  4.0074862250f,  0.02f, -0.5f, 1.0f,
              0.0025f, 0.025f, 0.0f, 0.0f,
              0.0f, 0.0f, 0.05f,
              25.0f, 0.98708396f, 0.0089418778f };   // 0.9935/1.0065, 0.009/1.0065
        break;
    case 1:  // M gate: e2 = exp((-35-Vn)/9)
        C = { -0.1602994490f, -5.6104807150f,  0.182f, 6.37f, 1.0f,
              0.0170329670329670f, 0.025f, 0.0f, 0.0f,
              0.0f, 0.0f, 0.05f,
              -35.0f, 0.86924620f, 0.076545632f };   // 0.93005/1.06995, 0.0819/1.06995
        break;
    case 2:  // H gate: E3 = exp((-90-Vn)/12); s = 0.00625(E3+br); alpha=0.0125E3
        C = { -0.1202245839f, -10.8202125510f, 0.0f, 1.0f, 0.0f,
              0.00625f, 0.0f, 0.00625f, 0.0f,
              0.0125f, 0.0f, 0.0f,
              NaNf, 0.0f, 0.0f };
        break;
    default: // y gate: E4 = exp((Vn+34)/12) (feeds lane2); s = 0.0025+0.025z
        C = {  0.1202245839f,   4.0876358530f, 0.0f, 1.0f, 0.0f,
              0.0f, 0.0025f, 0.0f, 0.025f,
              0.0f, 0.05f, 0.0f,
              NaNf, 0.0f, 0.0f };
        break;
    }

    float V = -70.0f;
    float g = (lane == 2) ? 1.0f : 0.0f;             // n=0, m=0, h=1, y=0

    op[0] = -70.0f;                                  // raw V0; pass 2 sigmoids it

    // 8-deep rotating prefetch: z0..z7 = z[t-1 .. t+6]
    float z0 = (0 <= N-2) ? zp[0]   : 0.0f;
    float z1 = (1 <= N-2) ? zp[128] : 0.0f;
    float z2 = (2 <= N-2) ? zp[256] : 0.0f;
    float z3 = (3 <= N-2) ? zp[384] : 0.0f;
    float z4 = (4 <= N-2) ? zp[512] : 0.0f;
    float z5 = (5 <= N-2) ? zp[640] : 0.0f;
    float z6 = (6 <= N-2) ? zp[768] : 0.0f;
    float z7 = (7 <= N-2) ? zp[896] : 0.0f;
    const float* zpre = zp + 8 * 128;                // next load: z[t+7] at t=1
    float* o = op + 128;
    int t = 1;
    // main: loads touch z indices t+7..t+10 <= N-1  ->  t <= N-11
    for (; t <= N - 11; t += 4) {
        float q0 = zpre[0];
        float q1 = zpre[128];
        float q2 = zpre[256];
        float q3 = zpre[384];
        zpre += 512;
        float v0 = hh_step4(V, g, z0, C);
        float v1 = hh_step4(V, g, z1, C);
        float v2 = hh_step4(V, g, z2, C);
        float v3 = hh_step4(V, g, z3, C);
        o[0] = v0; o[128] = v1; o[256] = v2; o[384] = v3;   // all lanes: same value
        o += 512;
        z0 = z4; z1 = z5; z2 = z6; z3 = z7;
        z4 = q0; z5 = q1; z6 = q2; z7 = q3;
    }
    // tail: per-step shift; refill z7 while in range
    for (; t < N; ++t) {
        float v0 = hh_step4(V, g, z0, C);
        *o = v0;
        o += 128;
        z0 = z1; z1 = z2; z2 = z3; z3 = z4; z4 = z5; z5 = z6; z6 = z7;
        z7 = (t + 7 <= N - 1) ? zpre[0] : 0.0f;      // z[t+7] for step t+8
        zpre += 128;
    }
}

// Pass 2: in-place sigmoid((v - VT)/KP) over the whole output, float4.
__global__ __launch_bounds__(256)
void sig_kernel(float4* __restrict__ v, int n4c) {
    int i = blockIdx.x * 256 + threadIdx.x;
    if (i < n4c) {
        float4 x = v[i];
        x.x = rcpf(1.0f + EXP2(__builtin_fmaf(-0.48089834664f, x.x, -9.6179669328f)));
        x.y = rcpf(1.0f + EXP2(__builtin_fmaf(-0.48089834664f, x.y, -9.6179669328f)));
        x.z = rcpf(1.0f + EXP2(__builtin_fmaf(-0.48089834664f, x.z, -9.6179669328f)));
        x.w = rcpf(1.0f + EXP2(__builtin_fmaf(-0.48089834664f, x.w, -9.6179669328f)));
        v[i] = x;
    }
}

extern "C" void kernel_launch(void* const* d_in, const int* in_sizes, int n_in,
                              void* d_out, int out_size, void* d_ws, size_t ws_size,
                              hipStream_t stream) {
    const float* z = (const float*)d_in[0];
    float* out = (float*)d_out;
    const int B = 32, L = 128;
    const int N = in_sizes[0] / (B * L);             // 2000
    dim3 grid(B * L * 4 / 64), block(64);            // 4 lanes/chain -> 256 waves
    hipLaunchKernelGGL(hh_kernel, grid, block, 0, stream, z, out, N);
    const int n4c = out_size / 4;                    // out_size divisible by 4
    dim3 sgrid((n4c + 255) / 256), sblock(256);
    hipLaunchKernelGGL(sig_kernel, sgrid, sblock, 0, stream, (float4*)out, n4c);
}